// Round 10
// baseline (8799.453 us; speedup 1.0000x reference)
//
#include <hip/hip_runtime.h>
#include <math.h>

#define NB 256
#define NH 2048
#define ND 8
#define NI 16
#define NT 128
#define NO 4
#define KKT 33           // K chunks of 64: 32 rec + 1 ext (w_in + zero pad) -> K = 2112
#define NTHR 512
#define NBLK 256

typedef __attribute__((ext_vector_type(4))) int i32x4;
typedef __attribute__((ext_vector_type(2))) long i64x2;

// ---- ws byte offsets ----
// W: [128 ht][33 kk][4 sp][64 lane][16B] i8 splits (per-block-contiguous slice = 135,168 B)
#define WSLICE   135168u
#define OFF_W    0u
#define SZ_W     (128u*WSLICE)                      // 17,301,504
#define OFF_SC   SZ_W                               // inv_scale f32[2048]
#define OFF_SCF  (OFF_SC + 8192u)                   // scale     f32[2048]
#define OFF_ZB   (OFF_SCF + 8192u)                  // 2 x Z[16 b16][33 kk][64 lane][16] i8
#define ZBUF_B   (16u*KKT*1024u)                    // 540,672 B per buffer
#define OFF_XS   (OFF_ZB + 2u*ZBUF_B)               // [NT][NB][NI] i8 encoder spikes
#define SZ_XS    ((unsigned)NT*NB*NI)
#define OFF_PIO  (OFF_XS + SZ_XS)                   // 2 x [256 b][128 ht][4 o] f32
#define PIOHALF  (NB*128*NO)                        // floats per half
#define OFF_CNT  (OFF_PIO + 2u*PIOHALF*4u)          // 2 barrier counters, 256B apart

// per-row scales over [w_rec | w_in]: s = 30 - exp(rowmax) -> 4 signed bytes exact
__global__ __launch_bounds__(512) void k_scale(const float* __restrict__ w_rec,
                                               const float* __restrict__ w_in,
                                               char* __restrict__ wsb) {
    const int gt = blockIdx.x * 512 + threadIdx.x;   // 256 blocks -> 2048 waves
    const int h = gt >> 6, lane = gt & 63;
    float m = 0.0f;
    for (int k = lane; k < NH; k += 64) m = fmaxf(m, fabsf(w_rec[h * NH + k]));
    if (lane < 16) m = fmaxf(m, fabsf(w_in[h * NI + lane]));
    #pragma unroll
    for (int d = 1; d < 64; d <<= 1) m = fmaxf(m, __shfl_xor(m, d, 64));
    if (lane == 0) {
        int e;
        frexpf(m, &e);
        int s = 30 - e;
        ((float*)(wsb + OFF_SCF))[h] = ldexpf(1.0f, s);
        ((float*)(wsb + OFF_SC))[h]  = ldexpf(1.0f, -s);
    }
}

// quantize + split into 4 i8 planes, per-block-contiguous fragment layout
__global__ __launch_bounds__(192) void k_pack(const float* __restrict__ w_rec,
                                              const float* __restrict__ w_in,
                                              char* __restrict__ wsb) {
    const int h = blockIdx.x, c = threadIdx.x;       // 2048 blocks, 132 chunks of 16 k
    if (c >= 132) return;
    const float scale = ((const float*)(wsb + OFF_SCF))[h];
    const int k0 = c * 16;
    const int kk = k0 >> 6, q = (k0 >> 4) & 3;
    unsigned pk[4][4] = {{0u,0u,0u,0u},{0u,0u,0u,0u},{0u,0u,0u,0u},{0u,0u,0u,0u}};
    #pragma unroll
    for (int u = 0; u < 16; ++u) {
        int k = k0 + u;
        float wv = 0.0f;
        if (k < NH) wv = w_rec[h * NH + k];
        else if (k < NH + NI) wv = w_in[h * NI + (k - NH)];
        int wq = __float2int_rn(wv * scale);
        int b0_ = (wq << 24) >> 24;  int r = (wq - b0_) >> 8;
        int b1_ = (r << 24) >> 24;   r = (r - b1_) >> 8;
        int b2_ = (r << 24) >> 24;   int b3_ = (r - b2_) >> 8;
        int bs[4] = {b0_, b1_, b2_, b3_};
        #pragma unroll
        for (int sp = 0; sp < 4; ++sp)
            pk[sp][u >> 2] |= ((unsigned)(unsigned char)bs[sp]) << ((u & 3) * 8);
    }
    char* w4 = wsb + OFF_W;
    unsigned base = (((unsigned)(h >> 4)) * KKT + (unsigned)kk) * 4096u
                  + ((unsigned)q * 16u + (unsigned)(h & 15)) * 16u;
    #pragma unroll
    for (int sp = 0; sp < 4; ++sp)
        *(i32x4*)(w4 + base + (unsigned)sp * 1024u) = *(const i32x4*)pk[sp];
}

__global__ __launch_bounds__(256) void k_init(const float* __restrict__ x,
                                              char* __restrict__ wsb) {
    const int g = blockIdx.x * 256 + threadIdx.x;   // 65536 threads
    unsigned* zb32 = (unsigned*)(wsb + OFF_ZB);     // 270,336 uints (both buffers)
    char* xsp = (char*)(wsb + OFF_XS);

    #pragma unroll
    for (int r = 0; r < 5; ++r) {
        unsigned off = (unsigned)g + (unsigned)r * 65536u;
        if (off < (2u * ZBUF_B / 4u)) zb32[off] = 0u;
    }
    if (g < 2) ((unsigned*)(wsb + OFF_CNT))[g * 64] = 0u;   // barrier counters

    if (g < NB * NI) {   // encoder cell (b, ci)
        const int b = g >> 4, ci = g & 15;
        float xv = x[b * ND + (ci & 7)];
        float c = (ci < 8) ? __fmul_rn(50.0f, xv) : __fmul_rn(-50.0f, xv);
        c = fmaxf(c, 0.0f);
        float ev = 0.0f;
        for (int t = 0; t < NT; ++t) {
            ev = __fadd_rn(ev, __fmul_rn(0.1f, __fsub_rn(c, ev)));
            float z = (__fsub_rn(ev, 1.0f) > 0.0f) ? 1.0f : 0.0f;
            xsp[t * (NB * NI) + g] = (z > 0.0f) ? (char)1 : (char)0;
            ev = (z > 0.0f) ? 0.0f : ev;
        }
    }
}

// xs[0] -> Z buffer 0 ext chunk (runs after k_init's zeroing)
__global__ __launch_bounds__(256) void k_init2(char* __restrict__ wsb) {
    const int b = threadIdx.x;                       // 256 threads
    char* zb0 = wsb + OFF_ZB;
    const char* xsp = wsb + OFF_XS;
    i32x4 xv = *(const i32x4*)(xsp + b * 16);
    *(i32x4*)(zb0 + (((unsigned)(b >> 4)) * KKT + 32u) * 1024u
                  + (unsigned)(b & 15) * 16u) = xv;
}

// persistent kernel: all 128 steps; weights in LDS; v/i in registers
__global__ __launch_bounds__(NTHR, 2) void k_persist(const float* __restrict__ w_out,
                                                     char* __restrict__ wsb,
                                                     float* __restrict__ out) {
    __shared__ char wlds[WSLICE];        // 135,168 B weight slice
    __shared__ float red[128 * 17];      // 8,704 B reduce / z staging
    __shared__ float woutlds[64];        // 4 o x 16 h

    const int tid = threadIdx.x;
    const int bt = blockIdx.x >> 7;      // 0..1  (128 b-rows each)
    const int ht = blockIdx.x & 127;     // 0..127 (16 h each)
    const int h0 = ht * 16;

    char* zb = wsb + OFF_ZB;
    const char* xsp = wsb + OFF_XS;
    float* pio = (float*)(wsb + OFF_PIO);
    unsigned* cnt = (unsigned*)(wsb + OFF_CNT);
    const float* inv_scale = (const float*)(wsb + OFF_SC);

    // one-time: weight slice -> LDS (flat copy, identical layout)
    {
        const char* gW = wsb + OFF_W + (unsigned)ht * WSLICE;
        for (int i = tid; i < (int)(WSLICE / 16u); i += NTHR)
            *(i32x4*)(wlds + (unsigned)i * 16u) = *(const i32x4*)(gW + (unsigned)i * 16u);
    }
    if (tid < 64) woutlds[tid] = w_out[(tid >> 4) * NH + h0 + (tid & 15)];

    const int w = tid >> 6, lane = tid & 63;
    const int kw = w & 1, bw = w >> 1;   // 2 K-halves x 4 b-groups
    const int lk = lane >> 4, lh = lane & 15;
    const float inv = inv_scale[h0 + lh];

    // per-thread LIF state: b_local = tid>>2, h = h0 + (tid&3)*4 + j
    float vmem[4] = {0.f, 0.f, 0.f, 0.f}, icur[4] = {0.f, 0.f, 0.f, 0.f};
    // readout owner state (ht<8, tid<64): b = bt*128 + ht + (tid>>2)*8, o = tid&3
    float vo = 0.0f, io = 0.0f, mxv = -3.0e38f;

    __syncthreads();

    for (int t = 0; t < NT; ++t) {
        const char* zr = zb + (t & 1) * ZBUF_B;
        char* zw = zb + ((t + 1) & 1) * ZBUF_B;
        float* pw = pio + (t & 1) * PIOHALF;

        // (1) LI readout update for step t-1 (owners only)
        if (t > 0 && ht < 8 && tid < 64) {
            const int bg = bt * 128 + ht + (tid >> 2) * 8;
            const int o = tid & 3;
            const float* pr = pio + ((t - 1) & 1) * PIOHALF + (unsigned)bg * 512u + o;
            float s = 0.0f;
            #pragma unroll
            for (int j = 0; j < 128; ++j) s += pr[j * 4];
            float von = __fadd_rn(vo, __fmul_rn(0.1f, __fsub_rn(io, vo)));  // old io
            io = __fadd_rn(__fmul_rn(io, 0.8f), s);
            vo = von;
            mxv = fmaxf(mxv, von);
        }

        // (2) xs[t+1] -> next z-buffer ext chunk (one block per bt group)
        if (ht == 8 && t + 1 < NT && tid < 128) {
            const int bg = bt * 128 + tid;
            i32x4 xv = *(const i32x4*)(xsp + ((t + 1) * NB + bg) * 16);
            *(i32x4*)(zw + (((unsigned)(bg >> 4)) * KKT + 32u) * 1024u
                         + (unsigned)(bg & 15) * 16u) = xv;
        }

        // (3) i8 MFMA GEMM: wave (kw,bw) = K-half x 2 b16
        i32x4 acc[2][4];
        #pragma unroll
        for (int rb = 0; rb < 2; ++rb)
            #pragma unroll
            for (int sp = 0; sp < 4; ++sp) acc[rb][sp] = (i32x4){0, 0, 0, 0};

        const char* zA = zr + ((unsigned)(bt * 8 + bw * 2) * KKT) * 1024u
                       + (unsigned)lane * 16u;
        const int kkbeg = kw * 17, kkend = kw ? 33 : 17;
        for (int kk = kkbeg; kk < kkend; ++kk) {
            i64x2 a0 = *(const i64x2*)(zA + (unsigned)kk * 1024u);
            i64x2 a1 = *(const i64x2*)(zA + (unsigned)(KKT + kk) * 1024u);
            #pragma unroll
            for (int sp = 0; sp < 4; ++sp) {
                i64x2 bf = *(const i64x2*)(wlds + (((unsigned)kk * 4u + (unsigned)sp) << 10)
                                                + (unsigned)lane * 16u);
                acc[0][sp] = __builtin_amdgcn_mfma_i32_16x16x32_i8(
                    a0[0], bf[0], acc[0][sp], 0, 0, 0);
                acc[0][sp] = __builtin_amdgcn_mfma_i32_16x16x32_i8(
                    a0[1], bf[1], acc[0][sp], 0, 0, 0);
                acc[1][sp] = __builtin_amdgcn_mfma_i32_16x16x32_i8(
                    a1[0], bf[0], acc[1][sp], 0, 0, 0);
                acc[1][sp] = __builtin_amdgcn_mfma_i32_16x16x32_i8(
                    a1[1], bf[1], acc[1][sp], 0, 0, 0);
            }
        }

        // combine splits -> f32, two-phase cross-kw reduce in LDS
        float fc[2][4];
        #pragma unroll
        for (int rb = 0; rb < 2; ++rb)
            #pragma unroll
            for (int r = 0; r < 4; ++r) {
                float f = fmaf((float)acc[rb][3][r], 16777216.0f,
                          fmaf((float)acc[rb][2][r], 65536.0f,
                          fmaf((float)acc[rb][1][r], 256.0f,
                               (float)acc[rb][0][r])));
                fc[rb][r] = f * inv;
            }
        if (kw == 1) {
            #pragma unroll
            for (int rb = 0; rb < 2; ++rb)
                #pragma unroll
                for (int r = 0; r < 4; ++r)
                    red[((bw * 2 + rb) * 16 + lk * 4 + r) * 17 + lh] = fc[rb][r];
        }
        __syncthreads();
        if (kw == 0) {
            #pragma unroll
            for (int rb = 0; rb < 2; ++rb)
                #pragma unroll
                for (int r = 0; r < 4; ++r) {
                    int ro = ((bw * 2 + rb) * 16 + lk * 4 + r) * 17 + lh;
                    red[ro] = fc[rb][r] + red[ro];
                }
        }
        __syncthreads();

        // (4) LIF update (v,i in registers); z bits back into red
        const int bb = tid >> 2, hb4 = (tid & 3) * 4;
        float zn4[4];
        #pragma unroll
        for (int j = 0; j < 4; ++j) {
            float accv = red[bb * 17 + hb4 + j];
            float vd = __fadd_rn(vmem[j], __fmul_rn(0.1f, __fsub_rn(icur[j], vmem[j])));
            float zn = (__fsub_rn(vd, 1.0f) > 0.0f) ? 1.0f : 0.0f;
            vmem[j] = (zn > 0.0f) ? 0.0f : vd;
            icur[j] = __fadd_rn(__fmul_rn(icur[j], 0.8f), accv);   // c folded in GEMM
            zn4[j] = zn;
        }
        #pragma unroll
        for (int j = 0; j < 4; ++j) red[bb * 17 + hb4 + j] = zn4[j];
        __syncthreads();

        // (5) readout partial + z-fragment write
        {
            const int o = tid & 3;
            float s = 0.0f;
            #pragma unroll
            for (int h = 0; h < 16; ++h)
                s = fmaf(red[bb * 17 + h], woutlds[o * 16 + h], s);
            pw[(((unsigned)(bt * 128 + bb)) * 128u + (unsigned)ht) * 4u + (unsigned)o] = s;
        }
        if (tid < 128) {
            const int bg = bt * 128 + tid;
            unsigned uw[4] = {0u, 0u, 0u, 0u};
            #pragma unroll
            for (int h = 0; h < 16; ++h)
                uw[h >> 2] |= (red[tid * 17 + h] > 0.5f ? 1u : 0u) << ((h & 3) * 8);
            i32x4 zv = {(int)uw[0], (int)uw[1], (int)uw[2], (int)uw[3]};
            *(i32x4*)(zw + (((unsigned)(bg >> 4)) * KKT + (unsigned)(ht >> 2)) * 1024u
                         + ((unsigned)(ht & 3) * 16u + (unsigned)(bg & 15)) * 16u) = zv;
        }

        // (6) group barrier (128 blocks per bt), monotonic counter
        __threadfence();
        __syncthreads();
        if (tid == 0) {
            __hip_atomic_fetch_add(&cnt[bt * 64], 1u, __ATOMIC_RELEASE,
                                   __HIP_MEMORY_SCOPE_AGENT);
            const unsigned target = (unsigned)(t + 1) * 128u;
            while (__hip_atomic_load(&cnt[bt * 64], __ATOMIC_ACQUIRE,
                                     __HIP_MEMORY_SCOPE_AGENT) < target)
                __builtin_amdgcn_s_sleep(1);
        }
        __syncthreads();
    }

    // final voltage[127] + softmax (owners)
    if (ht < 8 && tid < 64) {
        float von = __fadd_rn(vo, __fmul_rn(0.1f, __fsub_rn(io, vo)));
        float mx = fmaxf(mxv, von);
        float mm = fmaxf(mx, __shfl_xor(mx, 1, 64));
        mm = fmaxf(mm, __shfl_xor(mm, 2, 64));
        float e = expf(__fsub_rn(mx, mm));
        float es = e;
        es += __shfl_xor(es, 1, 64);
        es += __shfl_xor(es, 2, 64);
        const int bg = bt * 128 + ht + (tid >> 2) * 8;
        out[bg * 4 + (tid & 3)] = e / es;
    }
}

extern "C" void kernel_launch(void* const* d_in, const int* in_sizes, int n_in,
                              void* d_out, int out_size, void* d_ws, size_t ws_size,
                              hipStream_t stream) {
    const float* x     = (const float*)d_in[0];
    const float* w_in  = (const float*)d_in[1];
    const float* w_rec = (const float*)d_in[2];
    const float* w_out = (const float*)d_in[3];
    float* out = (float*)d_out;
    char* wsb  = (char*)d_ws;

    k_scale<<<256, 512, 0, stream>>>(w_rec, w_in, wsb);
    k_pack<<<NH, 192, 0, stream>>>(w_rec, w_in, wsb);
    k_init<<<256, 256, 0, stream>>>(x, wsb);
    k_init2<<<1, 256, 0, stream>>>(wsb);
    k_persist<<<NBLK, NTHR, 0, stream>>>(w_out, wsb, out);
}

// Round 12
// 2390.321 us; speedup vs baseline: 3.6813x; 3.6813x over previous
//
#include <hip/hip_runtime.h>
#include <math.h>

#define NB 256
#define NH 2048
#define ND 8
#define NI 16
#define NT 128
#define NO 4
#define KKT 33           // K chunks of 64: 32 rec + 1 ext (w_in + zero pad) -> K = 2112
#define NTHR 512
#define NBLK 256

typedef __attribute__((ext_vector_type(4))) int i32x4;
typedef __attribute__((ext_vector_type(2))) long i64x2;

// ---- ws byte offsets ----
// W: [128 ht][33 kk][4 sp][64 lane][16B] i8 splits (per-block-contiguous slice = 135,168 B)
#define WSLICE   135168u
#define OFF_W    0u
#define SZ_W     (128u*WSLICE)                      // 17,301,504
#define OFF_SC   SZ_W                               // inv_scale f32[2048]
#define OFF_SCF  (OFF_SC + 8192u)                   // scale     f32[2048]
#define OFF_ZB   (OFF_SCF + 8192u)                  // 2 x Z[16 b16][33 kk][64 lane][16] i8
#define ZBUF_B   (16u*KKT*1024u)                    // 540,672 B per buffer
#define OFF_XS   (OFF_ZB + 2u*ZBUF_B)               // [NT][NB][NI] i8 encoder spikes
#define SZ_XS    ((unsigned)NT*NB*NI)
#define OFF_PIO  (OFF_XS + SZ_XS)                   // 2 x [256 b][128 ht][4 o] f32
#define PIOHALF  (NB*128*NO)                        // floats per half
#define OFF_FLG  (OFF_PIO + 2u*PIOHALF*4u)          // arrive[256] u32, go at [272]

// per-row scales over [w_rec | w_in]: s = 30 - exp(rowmax) -> 4 signed bytes exact
__global__ __launch_bounds__(512) void k_scale(const float* __restrict__ w_rec,
                                               const float* __restrict__ w_in,
                                               char* __restrict__ wsb) {
    const int gt = blockIdx.x * 512 + threadIdx.x;   // 256 blocks -> 2048 waves
    const int h = gt >> 6, lane = gt & 63;
    float m = 0.0f;
    for (int k = lane; k < NH; k += 64) m = fmaxf(m, fabsf(w_rec[h * NH + k]));
    if (lane < 16) m = fmaxf(m, fabsf(w_in[h * NI + lane]));
    #pragma unroll
    for (int d = 1; d < 64; d <<= 1) m = fmaxf(m, __shfl_xor(m, d, 64));
    if (lane == 0) {
        int e;
        frexpf(m, &e);
        int s = 30 - e;
        ((float*)(wsb + OFF_SCF))[h] = ldexpf(1.0f, s);
        ((float*)(wsb + OFF_SC))[h]  = ldexpf(1.0f, -s);
    }
}

// quantize + split into 4 i8 planes, per-block-contiguous fragment layout
__global__ __launch_bounds__(192) void k_pack(const float* __restrict__ w_rec,
                                              const float* __restrict__ w_in,
                                              char* __restrict__ wsb) {
    const int h = blockIdx.x, c = threadIdx.x;       // 2048 blocks, 132 chunks of 16 k
    if (c >= 132) return;
    const float scale = ((const float*)(wsb + OFF_SCF))[h];
    const int k0 = c * 16;
    const int kk = k0 >> 6, q = (k0 >> 4) & 3;
    unsigned pk[4][4] = {{0u,0u,0u,0u},{0u,0u,0u,0u},{0u,0u,0u,0u},{0u,0u,0u,0u}};
    #pragma unroll
    for (int u = 0; u < 16; ++u) {
        int k = k0 + u;
        float wv = 0.0f;
        if (k < NH) wv = w_rec[h * NH + k];
        else if (k < NH + NI) wv = w_in[h * NI + (k - NH)];
        int wq = __float2int_rn(wv * scale);
        int b0_ = (wq << 24) >> 24;  int r = (wq - b0_) >> 8;
        int b1_ = (r << 24) >> 24;   r = (r - b1_) >> 8;
        int b2_ = (r << 24) >> 24;   int b3_ = (r - b2_) >> 8;
        int bs[4] = {b0_, b1_, b2_, b3_};
        #pragma unroll
        for (int sp = 0; sp < 4; ++sp)
            pk[sp][u >> 2] |= ((unsigned)(unsigned char)bs[sp]) << ((u & 3) * 8);
    }
    char* w4 = wsb + OFF_W;
    unsigned base = (((unsigned)(h >> 4)) * KKT + (unsigned)kk) * 4096u
                  + ((unsigned)q * 16u + (unsigned)(h & 15)) * 16u;
    #pragma unroll
    for (int sp = 0; sp < 4; ++sp)
        *(i32x4*)(w4 + base + (unsigned)sp * 1024u) = *(const i32x4*)pk[sp];
}

__global__ __launch_bounds__(256) void k_init(const float* __restrict__ x,
                                              char* __restrict__ wsb) {
    const int g = blockIdx.x * 256 + threadIdx.x;   // 65536 threads
    unsigned* zb32 = (unsigned*)(wsb + OFF_ZB);     // 270,336 uints (both buffers)
    char* xsp = (char*)(wsb + OFF_XS);

    #pragma unroll
    for (int r = 0; r < 5; ++r) {
        unsigned off = (unsigned)g + (unsigned)r * 65536u;
        if (off < (2u * ZBUF_B / 4u)) zb32[off] = 0u;
    }
    if (g < 512) ((unsigned*)(wsb + OFF_FLG))[g] = 0u;   // arrive flags + go

    if (g < NB * NI) {   // encoder cell (b, ci)
        const int b = g >> 4, ci = g & 15;
        float xv = x[b * ND + (ci & 7)];
        float c = (ci < 8) ? __fmul_rn(50.0f, xv) : __fmul_rn(-50.0f, xv);
        c = fmaxf(c, 0.0f);
        float ev = 0.0f;
        for (int t = 0; t < NT; ++t) {
            ev = __fadd_rn(ev, __fmul_rn(0.1f, __fsub_rn(c, ev)));
            float z = (__fsub_rn(ev, 1.0f) > 0.0f) ? 1.0f : 0.0f;
            xsp[t * (NB * NI) + g] = (z > 0.0f) ? (char)1 : (char)0;
            ev = (z > 0.0f) ? 0.0f : ev;
        }
    }
}

// xs[0] -> Z buffer 0 ext chunk (runs after k_init's zeroing)
__global__ __launch_bounds__(256) void k_init2(char* __restrict__ wsb) {
    const int b = threadIdx.x;                       // 256 threads
    char* zb0 = wsb + OFF_ZB;
    const char* xsp = wsb + OFF_XS;
    i32x4 xv = *(const i32x4*)(xsp + b * 16);
    *(i32x4*)(zb0 + (((unsigned)(b >> 4)) * KKT + 32u) * 1024u
                  + (unsigned)(b & 15) * 16u) = xv;
}

// persistent kernel: all 128 steps; weights in LDS; v/i in registers
__global__ __launch_bounds__(NTHR, 2) void k_persist(const float* __restrict__ w_out,
                                                     char* __restrict__ wsb,
                                                     float* __restrict__ out) {
    __shared__ char wlds[WSLICE];        // 135,168 B weight slice
    __shared__ float red[128 * 17];      // 8,704 B reduce / z staging
    __shared__ float woutlds[64];        // 4 o x 16 h

    const int tid = threadIdx.x;
    const int blk = blockIdx.x;
    const int bt = blk >> 7;             // 0..1  (128 b-rows each)
    const int ht = blk & 127;            // 0..127 (16 h each)
    const int h0 = ht * 16;

    char* zb = wsb + OFF_ZB;
    const char* xsp = wsb + OFF_XS;
    float* pio = (float*)(wsb + OFF_PIO);
    unsigned* arrive = (unsigned*)(wsb + OFF_FLG);
    unsigned* goflag = arrive + 272;
    const float* inv_scale = (const float*)(wsb + OFF_SC);

    // one-time: weight slice -> LDS (flat copy, identical layout)
    {
        const char* gW = wsb + OFF_W + (unsigned)ht * WSLICE;
        for (int i = tid; i < (int)(WSLICE / 16u); i += NTHR)
            *(i32x4*)(wlds + (unsigned)i * 16u) = *(const i32x4*)(gW + (unsigned)i * 16u);
    }
    if (tid < 64) woutlds[tid] = w_out[(tid >> 4) * NH + h0 + (tid & 15)];

    const int w = tid >> 6, lane = tid & 63;
    const int kw = w & 1, bw = w >> 1;   // 2 K-halves x 4 b-groups
    const int lk = lane >> 4, lh = lane & 15;
    const unsigned lane16 = (unsigned)lane * 16u;
    const float inv = inv_scale[h0 + lh];

    // per-thread LIF state: b_local = tid>>2, h = h0 + (tid&3)*4 + j
    float vmem[4] = {0.f, 0.f, 0.f, 0.f}, icur[4] = {0.f, 0.f, 0.f, 0.f};
    // readout owner state (ht<8, tid<64): b = bt*128 + ht + (tid>>2)*8, o = tid&3
    float vo = 0.0f, io = 0.0f, mxv = -3.0e38f;

    __syncthreads();

    for (int t = 0; t < NT; ++t) {
        const char* zr = zb + (t & 1) * ZBUF_B;
        char* zw = zb + ((t + 1) & 1) * ZBUF_B;
        float* pw = pio + (t & 1) * PIOHALF;

        // (1) LI readout update for step t-1 (owners only)
        if (t > 0 && ht < 8 && tid < 64) {
            const int bg = bt * 128 + ht + (tid >> 2) * 8;
            const int o = tid & 3;
            const float* pr = pio + ((t - 1) & 1) * PIOHALF + (unsigned)bg * 512u + o;
            float s = 0.0f;
            #pragma unroll
            for (int j = 0; j < 128; ++j) s += pr[j * 4];
            float von = __fadd_rn(vo, __fmul_rn(0.1f, __fsub_rn(io, vo)));  // old io
            io = __fadd_rn(__fmul_rn(io, 0.8f), s);
            vo = von;
            mxv = fmaxf(mxv, von);
        }

        // (2) xs[t+1] -> next z-buffer ext chunk (one block per bt group)
        if (ht == 8 && t + 1 < NT && tid < 128) {
            const int bg = bt * 128 + tid;
            i32x4 xv = *(const i32x4*)(xsp + ((t + 1) * NB + bg) * 16);
            *(i32x4*)(zw + (((unsigned)(bg >> 4)) * KKT + 32u) * 1024u
                         + (unsigned)(bg & 15) * 16u) = xv;
        }

        // (3) i8 MFMA GEMM: wave (kw,bw) = K-half x 2 b16; depth-1 A prefetch
        i32x4 acc[2][4];
        #pragma unroll
        for (int rb = 0; rb < 2; ++rb)
            #pragma unroll
            for (int sp = 0; sp < 4; ++sp) acc[rb][sp] = (i32x4){0, 0, 0, 0};

        const char* zA = zr + ((unsigned)(bt * 8 + bw * 2) * KKT) * 1024u + lane16;
        const int kkbeg = kw * 17;
        const int trips = 17 - kw;       // kw0: kk 0..16, kw1: kk 17..32
        i64x2 a0 = *(const i64x2*)(zA + (unsigned)kkbeg * 1024u);
        i64x2 a1 = *(const i64x2*)(zA + (unsigned)(KKT + kkbeg) * 1024u);
        #pragma unroll 4
        for (int kx = 0; kx < trips; ++kx) {
            i64x2 n0 = a0, n1 = a1;
            if (kx + 1 < trips) {
                const unsigned on = (unsigned)(kkbeg + kx + 1) * 1024u;
                n0 = *(const i64x2*)(zA + on);
                n1 = *(const i64x2*)(zA + (unsigned)KKT * 1024u + on);
            }
            const unsigned o = (unsigned)(kkbeg + kx) * 1024u;
            #pragma unroll
            for (int sp = 0; sp < 4; ++sp) {
                i64x2 bf = *(const i64x2*)(wlds + o * 4u + ((unsigned)sp << 10) + lane16);
                acc[0][sp] = __builtin_amdgcn_mfma_i32_16x16x32_i8(
                    a0[0], bf[0], acc[0][sp], 0, 0, 0);
                acc[0][sp] = __builtin_amdgcn_mfma_i32_16x16x32_i8(
                    a0[1], bf[1], acc[0][sp], 0, 0, 0);
                acc[1][sp] = __builtin_amdgcn_mfma_i32_16x16x32_i8(
                    a1[0], bf[0], acc[1][sp], 0, 0, 0);
                acc[1][sp] = __builtin_amdgcn_mfma_i32_16x16x32_i8(
                    a1[1], bf[1], acc[1][sp], 0, 0, 0);
            }
            a0 = n0; a1 = n1;
        }

        // combine splits -> f32, two-phase cross-kw reduce in LDS
        float fc[2][4];
        #pragma unroll
        for (int rb = 0; rb < 2; ++rb)
            #pragma unroll
            for (int r = 0; r < 4; ++r) {
                float f = fmaf((float)acc[rb][3][r], 16777216.0f,
                          fmaf((float)acc[rb][2][r], 65536.0f,
                          fmaf((float)acc[rb][1][r], 256.0f,
                               (float)acc[rb][0][r])));
                fc[rb][r] = f * inv;
            }
        if (kw == 1) {
            #pragma unroll
            for (int rb = 0; rb < 2; ++rb)
                #pragma unroll
                for (int r = 0; r < 4; ++r)
                    red[((bw * 2 + rb) * 16 + lk * 4 + r) * 17 + lh] = fc[rb][r];
        }
        __syncthreads();
        if (kw == 0) {
            #pragma unroll
            for (int rb = 0; rb < 2; ++rb)
                #pragma unroll
                for (int r = 0; r < 4; ++r) {
                    int ro = ((bw * 2 + rb) * 16 + lk * 4 + r) * 17 + lh;
                    red[ro] = fc[rb][r] + red[ro];
                }
        }
        __syncthreads();

        // (4) LIF update (v,i in registers); z bits back into red
        const int bb = tid >> 2, hb4 = (tid & 3) * 4;
        float zn4[4];
        #pragma unroll
        for (int j = 0; j < 4; ++j) {
            float accv = red[bb * 17 + hb4 + j];
            float vd = __fadd_rn(vmem[j], __fmul_rn(0.1f, __fsub_rn(icur[j], vmem[j])));
            float zn = (__fsub_rn(vd, 1.0f) > 0.0f) ? 1.0f : 0.0f;
            vmem[j] = (zn > 0.0f) ? 0.0f : vd;
            icur[j] = __fadd_rn(__fmul_rn(icur[j], 0.8f), accv);   // c folded in GEMM
            zn4[j] = zn;
        }
        #pragma unroll
        for (int j = 0; j < 4; ++j) red[bb * 17 + hb4 + j] = zn4[j];
        __syncthreads();

        // (5) readout partial + z-fragment write
        {
            const int o = tid & 3;
            float s = 0.0f;
            #pragma unroll
            for (int h = 0; h < 16; ++h)
                s = fmaf(red[bb * 17 + h], woutlds[o * 16 + h], s);
            pw[(((unsigned)(bt * 128 + bb)) * 128u + (unsigned)ht) * 4u + (unsigned)o] = s;
        }
        if (tid < 128) {
            const int bg = bt * 128 + tid;
            unsigned uw[4] = {0u, 0u, 0u, 0u};
            #pragma unroll
            for (int h = 0; h < 16; ++h)
                uw[h >> 2] |= (red[tid * 17 + h] > 0.5f ? 1u : 0u) << ((h & 3) * 8);
            i32x4 zv = {(int)uw[0], (int)uw[1], (int)uw[2], (int)uw[3]};
            *(i32x4*)(zw + (((unsigned)(bg >> 4)) * KKT + (unsigned)(ht >> 2)) * 1024u
                         + ((unsigned)(ht & 3) * 16u + (unsigned)(bg & 15)) * 16u) = zv;
        }

        // (6) grid barrier: slot flags + single go flag; one wbl2/invl2 per block
        __syncthreads();   // drains vmcnt(0): all z/pio stores at least in L2
        if (tid == 0) {
            __builtin_amdgcn_fence(__ATOMIC_RELEASE, "agent");   // buffer_wbl2
            __hip_atomic_store(&arrive[blk], (unsigned)(t + 1),
                               __ATOMIC_RELAXED, __HIP_MEMORY_SCOPE_AGENT);
        }
        if (blk == 0 && tid < 256) {
            while (__hip_atomic_load(&arrive[tid], __ATOMIC_RELAXED,
                                     __HIP_MEMORY_SCOPE_AGENT) < (unsigned)(t + 1))
                __builtin_amdgcn_s_sleep(1);
        }
        __syncthreads();   // block 0: gate go-store on all 256 polls done
        if (blk == 0 && tid == 0)
            __hip_atomic_store(goflag, (unsigned)(t + 1),
                               __ATOMIC_RELAXED, __HIP_MEMORY_SCOPE_AGENT);
        if (tid == 0) {
            while (__hip_atomic_load(goflag, __ATOMIC_RELAXED,
                                     __HIP_MEMORY_SCOPE_AGENT) < (unsigned)(t + 1))
                __builtin_amdgcn_s_sleep(1);
            __builtin_amdgcn_fence(__ATOMIC_ACQUIRE, "agent");   // buffer_inv
        }
        __syncthreads();
    }

    // final voltage[127] + softmax (owners)
    if (ht < 8 && tid < 64) {
        float von = __fadd_rn(vo, __fmul_rn(0.1f, __fsub_rn(io, vo)));
        float mx = fmaxf(mxv, von);
        float mm = fmaxf(mx, __shfl_xor(mx, 1, 64));
        mm = fmaxf(mm, __shfl_xor(mm, 2, 64));
        float e = expf(__fsub_rn(mx, mm));
        float es = e;
        es += __shfl_xor(es, 1, 64);
        es += __shfl_xor(es, 2, 64);
        const int bg = bt * 128 + ht + (tid >> 2) * 8;
        out[bg * 4 + (tid & 3)] = e / es;
    }
}

extern "C" void kernel_launch(void* const* d_in, const int* in_sizes, int n_in,
                              void* d_out, int out_size, void* d_ws, size_t ws_size,
                              hipStream_t stream) {
    const float* x     = (const float*)d_in[0];
    const float* w_in  = (const float*)d_in[1];
    const float* w_rec = (const float*)d_in[2];
    const float* w_out = (const float*)d_in[3];
    float* out = (float*)d_out;
    char* wsb  = (char*)d_ws;

    k_scale<<<256, 512, 0, stream>>>(w_rec, w_in, wsb);
    k_pack<<<NH, 192, 0, stream>>>(w_rec, w_in, wsb);
    k_init<<<256, 256, 0, stream>>>(x, wsb);
    k_init2<<<1, 256, 0, stream>>>(wsb);
    k_persist<<<NBLK, NTHR, 0, stream>>>(w_out, wsb, out);
}